// Round 6
// baseline (315.981 us; speedup 1.0000x reference)
//
#include <hip/hip_runtime.h>
#include <hip/hip_bf16.h>

// Problem constants
#define DMODEL 1024
#define NHEADS 16
#define HDIM   64
#define SEQ    2048
#define BATCH  2
#define MROWS  (SEQ*BATCH)   // 4096

typedef unsigned int u32;
typedef unsigned short u16;
typedef __attribute__((ext_vector_type(8))) short bfrag;    // 8 bf16 (A/B frag)
typedef __attribute__((ext_vector_type(4))) float f32x4;    // 16x16 C/D frag
typedef __attribute__((ext_vector_type(16))) float f32x16;  // 32x32 C/D frag
typedef union { u32 u[4]; bfrag f; } fragu;

#define LOG2E 1.44269504088896341f

// bf16 split helpers (RTN-even hi). x ~= hi + lo
__device__ __forceinline__ u32 f2bf(float x) {
    unsigned u = __float_as_uint(x);
    return (u + 0x7fffu + ((u >> 16) & 1u)) >> 16;
}
__device__ __forceinline__ float bf2f(u32 h) {
    return __uint_as_float(h << 16);
}
// packed 2xf32 -> 2xbf16 (v_cvt_pk_bf16_f32 on gfx950), a=low, b=high
__device__ __forceinline__ u32 pk2bf(float a, float b) {
    __hip_bfloat162 t = __float22bfloat162_rn(make_float2(a, b));
    u32 r;
    __builtin_memcpy(&r, &t, 4);
    return r;
}
__device__ __forceinline__ float fexp2(float x) {
#if __has_builtin(__builtin_amdgcn_exp2f)
    return __builtin_amdgcn_exp2f(x);
#else
    return exp2f(x);
#endif
}
// pack top-16 bits of two fp32 into one u32 (v_perm_b32)
__device__ __forceinline__ u32 pkhi(u32 u0, u32 u1) {
#if __has_builtin(__builtin_amdgcn_perm)
    return __builtin_amdgcn_perm(u1, u0, 0x07060302u);
#else
    return (u0 >> 16) | (u1 & 0xffff0000u);
#endif
}

// async global->LDS, 16B/lane; LDS dest = wave-uniform base (+lane*16 by HW)
__device__ __forceinline__ void gld16(const void* g, void* l) {
    __builtin_amdgcn_global_load_lds(
        (const __attribute__((address_space(1))) unsigned int*)g,
        (__attribute__((address_space(3))) unsigned int*)l, 16, 0, 0);
}

// ---------------------------------------------------------------------------
// BLOCKED hi/lo format: each row of 1024 elems = 32 groups of 32; group t
// occupies 64 u16: [32 hi][32 lo]. Frag reads are direct ds_read_b128
// (hi chunk = lquad, lo chunk = 4+lquad within the 128B group) — no unpack.
// ---------------------------------------------------------------------------

// Prep (wave-cooperative coalesced pack). Inputs are NO LONGER touched
// (d_in stays read-only — qkv reg-stages raw fp32 directly):
//  y=0..2 : Wq/Wk/Wv -> blocked hi/lo into ws   (512 blocks, 8KB/block)
//  y=3    : f64-accurate RoPE table              (256 blocks)
//  y=4    : Wo -> blocked hi/lo into ws          (512 blocks)
__global__ __launch_bounds__(256) void prep_kernel(
    const float* __restrict__ Wq, const float* __restrict__ Wk,
    const float* __restrict__ Wv, const float* __restrict__ Wo,
    u16* __restrict__ wqb, u16* __restrict__ wkb, u16* __restrict__ wvb,
    u16* __restrict__ wob, float2* __restrict__ tab)
{
    const int y = blockIdx.y;
    if (y == 3) {
        if (blockIdx.x >= 256) return;
        const int e = blockIdx.x * 256 + threadIdx.x;   // 65536 = 2048 s x 32 i
        const int s = e >> 5, i = e & 31;
        const double th = exp(-(double)i * (9.210340371976184 / 32.0)); // ln(1e4)/32
        double sn, cs;
        sincos((double)s * th, &sn, &cs);
        tab[e] = make_float2((float)sn, (float)cs);
        return;
    }
    const float* src = (y == 0) ? Wq : (y == 1) ? Wk : (y == 2) ? Wv : Wo;
    u16* dst = (y == 0) ? wqb : (y == 1) ? wkb : (y == 2) ? wvb : wob;
    const int lane = threadIdx.x & 63;
    const int wv   = threadIdx.x >> 6;                  // wave 0..3
    const int g8   = lane >> 3;                         // group within KB
    const int l8   = lane & 7;
    for (int r = 0; r < 2; ++r) {                       // 4MB / 512 blocks = 8KB
        const size_t kb = (size_t)blockIdx.x * 8 + (size_t)r * 4 + wv;
        const float4 x4 = *(const float4*)(src + kb * 256 + lane * 4);
        __align__(8) u16 hb[4];
        __align__(8) u16 lb[4];
        const float xs[4] = {x4.x, x4.y, x4.z, x4.w};
        #pragma unroll
        for (int i = 0; i < 4; ++i) {
            const u32 h = f2bf(xs[i]);
            hb[i] = (u16)h;
            lb[i] = (u16)f2bf(xs[i] - bf2f(h));
        }
        u16* o = dst + kb * 512 + g8 * 64 + l8 * 4;
        *(uint2*)o        = *(const uint2*)hb;
        *(uint2*)(o + 32) = *(const uint2*)lb;
    }
}

// ---------------------------------------------------------------------------
// Merged Q/K/V projection, NI=8 (BM=128, BN=128, 2 heads/block), 2-phase
// schedule, 2 blocks/CU (64KB LDS). A = RAW fp32 input, REG-STAGED:
//   issue A global_load_dwordx4 for tile t+1 -> MFMA(t) -> convert hi/lo in
//   registers (trunc-hi via v_perm + cvt_pk lo) -> ds_write swizzled blocked.
// Each wave's A rows (w*32..w*32+31) are consumed only by itself -> no
// cross-wave hazard on the A path; B (weights) keeps gld16 staging guarded
// by the barrier. d_in is never written (no re-poison restore cost).
// mode 0: RoPE(+scale)+hi/lo split -> [b][h][s][d] (Q/K), 2 heads/block
// mode 1: bf16-hi, LDS-transposed + key-quartet-permuted -> V^T (2 passes)
// ---------------------------------------------------------------------------
__global__ __launch_bounds__(256) void qkv_gemm_kernel(
    const float* __restrict__ query, const float* __restrict__ key,
    const float* __restrict__ value,
    const u16* __restrict__ Wqb, const u16* __restrict__ Wkb,
    const u16* __restrict__ Wvb,
    const float* __restrict__ bq, const float* __restrict__ bk,
    const float* __restrict__ bv, const float2* __restrict__ tab,
    u16* __restrict__ Qh, u16* __restrict__ Ql,
    u16* __restrict__ Kh, u16* __restrict__ Kl,
    u16* __restrict__ VTh)
{
    __shared__ u16 smem16[32768];   // 64 KB: sA 2x128x64, sB 2x128x64
    u16* sA = smem16;               // [h][128][64]
    u16* sB = smem16 + 16384;       // [h][128][64]

    const int z  = blockIdx.z;
    const float* Af   = (z == 0) ? query : (z == 1) ? key : value;
    const u16* Wb     = (z == 0) ? Wqb : (z == 1) ? Wkb : Wvb;
    const float* bias = (z == 0) ? bq : (z == 1) ? bk : bv;
    u16* Oh = (z == 0) ? Qh : (z == 1) ? Kh : VTh;
    u16* Ol = (z == 0) ? Ql : (z == 1) ? Kl : nullptr;
    const float rope_scale = (z == 0) ? 0.125f * LOG2E : 1.0f;
    const int mode = (z == 2) ? 1 : 0;

    const int tid   = threadIdx.x;
    const int w     = tid >> 6;
    const int lane  = tid & 63;
    const int lrow  = lane & 15;
    const int lquad = lane >> 4;

    // XCD-aware remap: 256 tiles/proj; per XCD 4 m-tiles x 8 n-tiles
    const int id   = blockIdx.x + 16 * blockIdx.y;  // 0..255
    const int xcd  = id & 7;
    const int jj   = id >> 3;                       // 0..31
    const int nblk = jj & 7;
    const int mblk = (xcd << 2) | (jj >> 3);        // 0..31
    const int n0   = nblk * 128;
    const int m0   = mblk * 128;

    // B staging coords: 8-row slabs, 8 chunks of 16B per 128B row-group
    const int srow8 = lane >> 3;
    const int sch   = (lane & 7) ^ srow8;

    // A reg-staging coords: lane -> (row-in-slab, k-quarter)
    const int l8r = lane >> 3;          // 0..7
    const int l8c = lane & 7;           // 0..7 -> 4 fp32 at k = l8c*4
    const int cA  = l8c >> 1;           // 16B chunk 0..3
    const int hA  = (l8c & 1) * 4;      // u16 offset within chunk

    // frag offsets (u16 units): hi chunk = lquad, lo chunk = 4+lquad
    int aoffh[2], aoffl[2], boffh[8], boffl[8];
    #pragma unroll
    for (int mi = 0; mi < 2; ++mi) {
        const int ra = w * 32 + mi * 16 + lrow;
        aoffh[mi] = ra * 64 + ((lquad ^ (ra & 7)) << 3);
        aoffl[mi] = ra * 64 + (((lquad + 4) ^ (ra & 7)) << 3);
    }
    #pragma unroll
    for (int ni = 0; ni < 8; ++ni) {
        const int rb = ni * 16 + lrow;
        boffh[ni] = rb * 64 + ((lquad ^ (rb & 7)) << 3);
        boffl[ni] = rb * 64 + (((lquad + 4) ^ (rb & 7)) << 3);
    }

    f32x4 acc[2][8] = {};

    // B: 4 gld16/wave/tile into sB half
    auto stageB = [&](int t) {
        const int h = t & 1;
        #pragma unroll
        for (int i = 0; i < 4; ++i) {
            const int slab = w * 4 + i;
            const int row  = slab * 8 + srow8;
            gld16(Wb + (size_t)(n0 + row) * 2048 + t * 64 + sch * 8,
                  sB + h * 8192 + slab * 512);
        }
    };
    // A: 4 dwordx4/wave/tile (coalesced: 8 lanes x 128B per row, 8 rows/iter)
    auto loadA = [&](int t, float4* va) {
        #pragma unroll
        for (int i = 0; i < 4; ++i) {
            const int r = w * 32 + i * 8 + l8r;
            va[i] = ((const float4*)Af)[(size_t)(m0 + r) * 256 + t * 8 + l8c];
        }
    };
    // convert trunc-hi + rn-lo, ds_write swizzled blocked (wave-local rows)
    auto writeA = [&](int t, const float4* va) {
        const int h = t & 1;
        #pragma unroll
        for (int i = 0; i < 4; ++i) {
            const int r = w * 32 + i * 8 + l8r;
            const u32 u0 = __float_as_uint(va[i].x);
            const u32 u1 = __float_as_uint(va[i].y);
            const u32 u2 = __float_as_uint(va[i].z);
            const u32 u3 = __float_as_uint(va[i].w);
            uint2 hv, lv;
            hv.x = pkhi(u0, u1);
            hv.y = pkhi(u2, u3);
            const float r0 = va[i].x - __uint_as_float(u0 & 0xffff0000u);
            const float r1 = va[i].y - __uint_as_float(u1 & 0xffff0000u);
            const float r2 = va[i].z - __uint_as_float(u2 & 0xffff0000u);
            const float r3 = va[i].w - __uint_as_float(u3 & 0xffff0000u);
            lv.x = pk2bf(r0, r1);
            lv.y = pk2bf(r2, r3);
            u16* base = sA + h * 8192 + r * 64;
            *(uint2*)(base + ((cA ^ (r & 7)) << 3) + hA)       = hv;
            *(uint2*)(base + (((cA + 4) ^ (r & 7)) << 3) + hA) = lv;
        }
    };

    // prologue: buf 0
    {
        float4 va[4];
        stageB(0);
        loadA(0, va);
        writeA(0, va);
    }
    for (int t = 0; t < 32; ++t) {
        __syncthreads();                 // buf t ready (vmcnt+lgkmcnt drained)
        float4 va[4];
        if (t < 31) {
            stageB(t + 1);               // async -> LDS
            loadA(t + 1, va);            // -> regs, lands during MFMA below
        }
        const int h = t & 1;
        const u16* sAh_ = sA + h * 8192;
        const u16* sBh_ = sB + h * 8192;

        bfrag ah[2], al[2], bh[8], bl[8];
        #pragma unroll
        for (int mi = 0; mi < 2; ++mi) {
            ah[mi] = *(const bfrag*)&sAh_[aoffh[mi]];
            al[mi] = *(const bfrag*)&sAh_[aoffl[mi]];
        }
        #pragma unroll
        for (int ni = 0; ni < 8; ++ni) {
            bh[ni] = *(const bfrag*)&sBh_[boffh[ni]];
            bl[ni] = *(const bfrag*)&sBh_[boffl[ni]];
        }

        #pragma unroll
        for (int mi = 0; mi < 2; ++mi)
            #pragma unroll
            for (int ni = 0; ni < 8; ++ni) {
                acc[mi][ni] = __builtin_amdgcn_mfma_f32_16x16x32_bf16(ah[mi], bh[ni], acc[mi][ni], 0, 0, 0);
                acc[mi][ni] = __builtin_amdgcn_mfma_f32_16x16x32_bf16(ah[mi], bl[ni], acc[mi][ni], 0, 0, 0);
                acc[mi][ni] = __builtin_amdgcn_mfma_f32_16x16x32_bf16(al[mi], bh[ni], acc[mi][ni], 0, 0, 0);
            }

        if (t < 31) writeA(t + 1, va);   // convert + ds_write buf t+1
    }

    float bn[8];
    #pragma unroll
    for (int ni = 0; ni < 8; ++ni) bn[ni] = bias[n0 + ni * 16 + lrow];

    if (mode == 0) {
        // RoPE + hi/lo split write; block spans 2 heads (64 cols each)
        #pragma unroll
        for (int mi = 0; mi < 2; ++mi)
            #pragma unroll
            for (int r = 0; r < 4; ++r) {
                const int mrow = w * 32 + mi * 16 + lquad * 4 + r;
                const int m  = m0 + mrow;
                const int bb = m & 1;
                const int sg = m >> 1;
                #pragma unroll
                for (int hh = 0; hh < 2; ++hh) {
                    const int head = nblk * 2 + hh;
                    const size_t ob = (((size_t)(bb * NHEADS + head) * SEQ) + sg) * HDIM;
                    #pragma unroll
                    for (int ni = 0; ni < 2; ++ni) {
                        const int i = ni * 16 + lrow;
                        const float2 sc = tab[(size_t)sg * 32 + i];
                        const float x1 = acc[mi][hh * 4 + ni][r]     + bn[hh * 4 + ni];
                        const float x2 = acc[mi][hh * 4 + ni + 2][r] + bn[hh * 4 + ni + 2];
                        // reference quirk: o2 = x1*sin - x2*cos
                        const float o1 = (x1 * sc.y - x2 * sc.x) * rope_scale;
                        const float o2 = (x1 * sc.x - x2 * sc.y) * rope_scale;
                        const u32 h1 = f2bf(o1);
                        const u32 h2 = f2bf(o2);
                        Oh[ob + i]      = (u16)h1;  Ol[ob + i]      = (u16)f2bf(o1 - bf2f(h1));
                        Oh[ob + i + 32] = (u16)h2;  Ol[ob + i + 32] = (u16)f2bf(o2 - bf2f(h2));
                    }
                }
            }
        return;
    }
    // mode 1: bf16-hi V^T, transposed via LDS (stride 65), key-quartet
    // permuted; two passes (one batch parity each), vb 33KB <= 64KB.
    __syncthreads();
    u32* vb = (u32*)smem16;
    for (int p = 0; p < 2; ++p) {
        if (p) __syncthreads();
        #pragma unroll
        for (int mi = 0; mi < 2; ++mi)
            #pragma unroll
            for (int r = 0; r < 4; ++r) {
                const int mrow = w * 32 + mi * 16 + lquad * 4 + r;
                const int bb = mrow & 1;
                const int sl = mrow >> 1;
                if (bb == p) {
                    #pragma unroll
                    for (int ni = 0; ni < 8; ++ni) {
                        const int d = ni * 16 + lrow;
                        vb[d * 65 + sl] = f2bf(acc[mi][ni][r] + bn[ni]);
                    }
                }
            }
        __syncthreads();
        #pragma unroll
        for (int rep = 0; rep < 4; ++rep) {
            const int c  = rep * 256 + tid;      // 1024 chunks per pass
            const int dc = c >> 3;               // 0..127
            const int s8 = c & 7;
            __align__(8) u16 hb[8];
            #pragma unroll
            for (int j = 0; j < 8; ++j)
                hb[j] = (u16)vb[dc * 65 + s8 * 8 + j];
            const int head = nblk * 2 + (dc >> 6);
            const int dd   = dc & 63;
            const size_t orow = ((size_t)(p * NHEADS + head) * HDIM + dd) * SEQ + (m0 >> 1);
            const int blk16 = (s8 >> 1) * 16;
            const int off   = (s8 & 1) * 4;
            *(uint2*)&Oh[orow + blk16 + off]     = *(const uint2*)&hb[0];
            *(uint2*)&Oh[orow + blk16 + 8 + off] = *(const uint2*)&hb[4];
        }
    }
}

// ---------------------------------------------------------------------------
// 2-phase GEMM body for out_gemm (blocked A via gld16): BM=128, BN=NI*16,
// mode 2 fp32 row-major output. Unchanged control.
// ---------------------------------------------------------------------------
template <int NI>
__device__ __forceinline__ void gemm_body(
    int id,
    const u16* __restrict__ Ab, const u16* __restrict__ Wb,
    const float* __restrict__ bias, float* __restrict__ Of,
    u16* smem16)
{
    u16* sA = smem16;               // 2 halves x 128 rows x 64 u16
    u16* sB = smem16 + 16384;       // 2 halves x (NI*16) rows x 64 u16

    const int tid   = threadIdx.x;
    const int w     = tid >> 6;
    const int lane  = tid & 63;
    const int lrow  = lane & 15;
    const int lquad = lane >> 4;

    const int NBLK = 1024 / (NI * 16);
    const int xcd  = id & 7;
    const int jj   = id >> 3;
    const int nblk = jj & (NBLK - 1);
    const int mblk = (xcd << 2) | (jj / NBLK);
    const int n0   = nblk * NI * 16;
    const int m0   = mblk * 128;

    const int srow8 = lane >> 3;
    const int sch   = (lane & 7) ^ srow8;

    int aoffh[2], aoffl[2], boffh[NI], boffl[NI];
    #pragma unroll
    for (int mi = 0; mi < 2; ++mi) {
        const int ra = w * 32 + mi * 16 + lrow;
        aoffh[mi] = ra * 64 + ((lquad ^ (ra & 7)) << 3);
        aoffl[mi] = ra * 64 + (((lquad + 4) ^ (ra & 7)) << 3);
    }
    #pragma unroll
    for (int ni = 0; ni < NI; ++ni) {
        const int rb = ni * 16 + lrow;
        boffh[ni] = rb * 64 + ((lquad ^ (rb & 7)) << 3);
        boffl[ni] = rb * 64 + (((lquad + 4) ^ (rb & 7)) << 3);
    }

    f32x4 acc[2][NI] = {};

    auto stage = [&](int t) {
        const int h = t & 1;
        #pragma unroll
        for (int i = 0; i < 4; ++i) {
            const int slab = w * 4 + i;
            const int row  = slab * 8 + srow8;
            gld16(Ab + (size_t)(m0 + row) * 2048 + t * 64 + sch * 8,
                  sA + h * 8192 + slab * 512);
        }
        #pragma unroll
        for (int i = 0; i < NI / 2; ++i) {
            const int slab = w * (NI / 2) + i;
            const int row  = slab * 8 + srow8;
            gld16(Wb + (size_t)(n0 + row) * 2048 + t * 64 + sch * 8,
                  sB + h * (NI * 1024) + slab * 512);
        }
    };

    stage(0);
    for (int t = 0; t < 32; ++t) {
        __syncthreads();
        if (t < 31) stage(t + 1);
        const int h = t & 1;
        const u16* sAh_ = sA + h * 8192;
        const u16* sBh_ = sB + h * (NI * 1024);

        bfrag ah[2], al[2], bh[NI], bl[NI];
        #pragma unroll
        for (int mi = 0; mi < 2; ++mi) {
            ah[mi] = *(const bfrag*)&sAh_[aoffh[mi]];
            al[mi] = *(const bfrag*)&sAh_[aoffl[mi]];
        }
        #pragma unroll
        for (int ni = 0; ni < NI; ++ni) {
            bh[ni] = *(const bfrag*)&sBh_[boffh[ni]];
            bl[ni] = *(const bfrag*)&sBh_[boffl[ni]];
        }

        #pragma unroll
        for (int mi = 0; mi < 2; ++mi)
            #pragma unroll
            for (int ni = 0; ni < NI; ++ni) {
                acc[mi][ni] = __builtin_amdgcn_mfma_f32_16x16x32_bf16(ah[mi], bh[ni], acc[mi][ni], 0, 0, 0);
                acc[mi][ni] = __builtin_amdgcn_mfma_f32_16x16x32_bf16(ah[mi], bl[ni], acc[mi][ni], 0, 0, 0);
                acc[mi][ni] = __builtin_amdgcn_mfma_f32_16x16x32_bf16(al[mi], bh[ni], acc[mi][ni], 0, 0, 0);
            }
    }

    float bn[NI];
    #pragma unroll
    for (int ni = 0; ni < NI; ++ni) bn[ni] = bias[n0 + ni * 16 + lrow];

    #pragma unroll
    for (int mi = 0; mi < 2; ++mi)
        #pragma unroll
        for (int r = 0; r < 4; ++r) {
            const int m = m0 + w * 32 + mi * 16 + lquad * 4 + r;
            #pragma unroll
            for (int ni = 0; ni < NI; ++ni)
                Of[(size_t)m * 1024 + n0 + ni * 16 + lrow] = acc[mi][ni][r] + bn[ni];
        }
}

// Final projection: A = attn output (blocked). NI=4 (BN=64, grid 512,
// 48KB LDS, 3 blocks/CU). Unchanged control.
__global__ __launch_bounds__(256) void out_gemm_kernel(
    const u16* __restrict__ Ab, const u16* __restrict__ Wb,
    const float* __restrict__ bias, float* __restrict__ Of)
{
    __shared__ u16 smem16[24576];                 // 48 KB
    const int id = blockIdx.x + 16 * blockIdx.y;
    gemm_body<4>(id, Ab, Wb, bias, Of, smem16);
}

// ---------------------------------------------------------------------------
// MFMA flash attention (non-split): 32x32x16, no-max softmax (exp2, Q
// pre-scaled by log2e/8), S^T/O^T form, double-buffered K/V tiles,
// register-P, permuted V^T (hi-only). Unchanged control.
// Block = 256 threads (4 waves) = 128 q-rows; grid 512; LDS 48 KB.
// ---------------------------------------------------------------------------
__global__ __launch_bounds__(256) void attn_mfma_kernel(
    const u16* __restrict__ Qh, const u16* __restrict__ Ql,
    const u16* __restrict__ Kh, const u16* __restrict__ Kl,
    const u16* __restrict__ Vh,
    u16* __restrict__ AOb)
{
    __shared__ u16 sKh[8192], sKl[8192];   // [buf][key][dh] swizzled
    __shared__ u16 sVh[8192];              // [buf][dh][key'] swizzled (permuted)

    const int tid  = threadIdx.x;
    const int w    = tid >> 6;             // 0..3
    const int lane = tid & 63;
    const int l31  = lane & 31;
    const int g    = lane >> 5;

    const int id = blockIdx.x + 16 * blockIdx.y;   // 0..511
    const int jj = id >> 3;                        // 0..63
    const int bh = ((id & 7) << 2) | (jj >> 4);
    const int qt = jj & 15;

    const size_t qg = ((size_t)bh * SEQ + qt * 128 + w * 32 + l31) * HDIM + g * 8;
    bfrag qfh[4], qfl[4];
    #pragma unroll
    for (int ks = 0; ks < 4; ++ks) {
        qfh[ks] = *(const bfrag*)&Qh[qg + ks * 16];
        qfl[ks] = *(const bfrag*)&Ql[qg + ks * 16];
    }

    const int srow   = lane >> 3;
    const int schunk = (lane & 7) ^ srow;
    const u16* gsrc = nullptr; u16* lbase = nullptr; size_t istep = 0, ktstep = 0;
    if (w == 0) {
        gsrc = Kh + ((size_t)bh * SEQ + srow) * HDIM + schunk * 8;
        istep = 8 * 64; ktstep = 64 * 64; lbase = sKh;
    } else if (w == 1) {
        gsrc = Kl + ((size_t)bh * SEQ + srow) * HDIM + schunk * 8;
        istep = 8 * 64; ktstep = 64 * 64; lbase = sKl;
    } else if (w == 2) {
        gsrc = Vh + ((size_t)bh * HDIM + srow) * SEQ + schunk * 8;
        istep = 8 * SEQ; ktstep = 64; lbase = sVh;
    }

    int koff[2][4];
    #pragma unroll
    for (int a = 0; a < 2; ++a) {
        const int row = a * 32 + l31;
        #pragma unroll
        for (int c = 0; c < 4; ++c)
            koff[a][c] = row * 64 + (((c * 2 + g) ^ (row & 7)) << 3);
    }

    f32x16 accO[2] = {};
    float l_loc = 0.0f;

    auto stage = [&](int kt) {
        if (w < 3) {
            const u16* gp = gsrc + (size_t)kt * ktstep;
            u16* dst = lbase + (kt & 1) * 4096;
            #pragma unroll
            for (int i = 0; i < 8; ++i)
                gld16(gp + (size_t)i * istep, dst + i * 512);
        }
    };

    stage(0);
    for (int kt = 0; kt < SEQ / 64; ++kt) {
        __syncthreads();                     // tile kt ready (vmcnt drained)
        if (kt < SEQ / 64 - 1) stage(kt + 1);
        const int po = (kt & 1) * 4096;

        // ---- S^T = K Q^T (Q pre-scaled by log2e/8) : lane=q, regs=keys ----
        f32x16 accS[2] = {};
        #pragma unroll
        for (int kg = 0; kg < 2; ++kg)
            #pragma unroll
            for (int ks = 0; ks < 4; ++ks) {
                const bfrag kh_ = *(const bfrag*)&sKh[po + koff[kg][ks]];
                const bfrag kl_ = *(const bfrag*)&sKl[po + koff[kg][ks]];
                accS[kg] = __builtin_amdgcn_mfma_f32_32x32x16_bf16(kh_, qfh[ks], accS[kg], 0, 0, 0);
                accS[kg] = __builtin_amdgcn_mfma_f32_32x32x16_bf16(kh_, qfl[ks], accS[kg], 0, 0, 0);
                accS[kg] = __builtin_amdgcn_mfma_f32_32x32x16_bf16(kl_, qfh[ks], accS[kg], 0, 0, 0);
            }

        // ---- p = exp2(s') in registers (lane=q, reg=key) ----
        float pv[2][16];
        #pragma unroll
        for (int kg = 0; kg < 2; ++kg)
            #pragma unroll
            for (int r = 0; r < 16; ++r) {
                const float p = fexp2(accS[kg][r]);
                pv[kg][r] = p;
                l_loc += p;
            }

        // ---- O^T += Vh^T P^T (no exchange: permuted V^T; hi-only) ----
        #pragma unroll
        for (int kp = 0; kp < 4; ++kp) {
            const int kg = kp >> 1;
            const int t8 = (kp & 1) * 8;
            fragu ph;
            #pragma unroll
            for (int j2 = 0; j2 < 4; ++j2)
                ph.u[j2] = pk2bf(pv[kg][t8 + 2 * j2], pv[kg][t8 + 2 * j2 + 1]);
            #pragma unroll
            for (int dt = 0; dt < 2; ++dt) {
                const bfrag vh = *(const bfrag*)&sVh[po + koff[dt][kp]];
                accO[dt] = __builtin_amdgcn_mfma_f32_32x32x16_bf16(vh, ph.f, accO[dt], 0, 0, 0);
            }
        }
    }

    // ---- l: combine complementary g-halves; write BLOCKED hi/lo output ----
    const float inv = 1.0f / (l_loc + __shfl_xor(l_loc, 32));

    const int b = bh >> 4;
    const int h = bh & 15;
    const int sg = qt * 128 + w * 32 + l31;
    const int rm = sg * BATCH + b;                 // output row (0..4095)
    #pragma unroll
    for (int dt = 0; dt < 2; ++dt)
        #pragma unroll
        for (int rq = 0; rq < 4; ++rq) {
            const int j0 = 8 * rq + 4 * g;         // pos within 32-group
            const int t  = h * 2 + dt;             // group index
            __align__(8) u16 hb[4];
            __align__(8) u16 lb[4];
            #pragma unroll
            for (int i2 = 0; i2 < 4; ++i2) {
                const float v = accO[dt][rq * 4 + i2] * inv;
                const u32 hh = f2bf(v);
                hb[i2] = (u16)hh;
                lb[i2] = (u16)f2bf(v - bf2f(hh));
            }
            u16* o = AOb + (size_t)rm * 2048 + t * 64 + j0;
            *(uint2*)o        = *(const uint2*)hb;
            *(uint2*)(o + 32) = *(const uint2*)lb;
        }
}

// ---------------------------------------------------------------------------
extern "C" void kernel_launch(void* const* d_in, const int* in_sizes, int n_in,
                              void* d_out, int out_size, void* d_ws, size_t ws_size,
                              hipStream_t stream)
{
    const float* query = (const float*)d_in[0];   // READ-ONLY (no in-place pack)
    const float* key   = (const float*)d_in[1];
    const float* value = (const float*)d_in[2];
    const float* Wq    = (const float*)d_in[3];
    const float* bq    = (const float*)d_in[4];
    const float* Wk    = (const float*)d_in[5];
    const float* bk    = (const float*)d_in[6];
    const float* Wv    = (const float*)d_in[7];
    const float* bv    = (const float*)d_in[8];
    const float* Wo    = (const float*)d_in[9];
    const float* bo    = (const float*)d_in[10];
    float* out = (float*)d_out;

    // 64 MB workspace, time-multiplexed (MB offsets):
    //  Wqb [0,4) Wkb [4,8) Wvb [8,12) tab [12,12.5)  -- dead after qkv
    //  Qh [16,24) Ql [24,32) Kh [32,40) Kl [40,48) VTh [48,56)
    //  Wob [56,60)          (written in prep, read by out_gemm — never aliased)
    //  AOb blocked [0,16)   (attn output; W-packs + tab dead after qkv)
    char* wsb = (char*)d_ws;
    const size_t MB = 1024 * 1024;
    u16* Wqb = (u16*)(wsb + 0 * MB);
    u16* Wkb = (u16*)(wsb + 4 * MB);
    u16* Wvb = (u16*)(wsb + 8 * MB);
    float2* tab = (float2*)(wsb + 12 * MB);
    u16* Qh  = (u16*)(wsb + 16 * MB); u16* Ql  = (u16*)(wsb + 24 * MB);
    u16* Kh  = (u16*)(wsb + 32 * MB); u16* Kl  = (u16*)(wsb + 40 * MB);
    u16* VTh = (u16*)(wsb + 48 * MB);
    u16* Wob = (u16*)(wsb + 56 * MB);
    u16* AOb = (u16*)(wsb + 0 * MB);

    // pack weights (incl. Wo) + RoPE table (inputs untouched)
    prep_kernel<<<dim3(512, 5), 256, 0, stream>>>(
        Wq, Wk, Wv, Wo, Wqb, Wkb, Wvb, Wob, tab);
    // merged Q/K/V projections (+RoPE for Q/K; Q pre-scaled; V writes V^T hi);
    // A = raw fp32, reg-staged with in-register hi/lo split
    qkv_gemm_kernel<<<dim3(16, 16, 3), 256, 0, stream>>>(
        query, key, value,
        Wqb, Wkb, Wvb, bq, bk, bv, tab, Qh, Ql, Kh, Kl, VTh);
    // attention -> blocked hi/lo (S,B,D)
    attn_mfma_kernel<<<dim3(16, 32), 256, 0, stream>>>(
        Qh, Ql, Kh, Kl, VTh, AOb);
    // output projection (NI=4: BN=64, 512 blocks)
    out_gemm_kernel<<<dim3(16, 32), 256, 0, stream>>>(AOb, Wob, bo, out);
}

// Round 7
// 295.833 us; speedup vs baseline: 1.0681x; 1.0681x over previous
//
#include <hip/hip_runtime.h>
#include <hip/hip_bf16.h>

// Problem constants
#define DMODEL 1024
#define NHEADS 16
#define HDIM   64
#define SEQ    2048
#define BATCH  2
#define MROWS  (SEQ*BATCH)   // 4096

typedef unsigned int u32;
typedef unsigned short u16;
typedef __attribute__((ext_vector_type(8))) short bfrag;    // 8 bf16 (A/B frag)
typedef __attribute__((ext_vector_type(4))) float f32x4;    // 16x16 C/D frag
typedef __attribute__((ext_vector_type(16))) float f32x16;  // 32x32 C/D frag
typedef union { u32 u[4]; bfrag f; } fragu;

#define LOG2E 1.44269504088896341f

// bf16 split helpers (RTN-even hi). x ~= hi + lo
__device__ __forceinline__ u32 f2bf(float x) {
    unsigned u = __float_as_uint(x);
    return (u + 0x7fffu + ((u >> 16) & 1u)) >> 16;
}
__device__ __forceinline__ float bf2f(u32 h) {
    return __uint_as_float(h << 16);
}
// packed 2xf32 -> 2xbf16 (v_cvt_pk_bf16_f32 on gfx950), a=low, b=high
__device__ __forceinline__ u32 pk2bf(float a, float b) {
    __hip_bfloat162 t = __float22bfloat162_rn(make_float2(a, b));
    u32 r;
    __builtin_memcpy(&r, &t, 4);
    return r;
}
__device__ __forceinline__ float fexp2(float x) {
#if __has_builtin(__builtin_amdgcn_exp2f)
    return __builtin_amdgcn_exp2f(x);
#else
    return exp2f(x);
#endif
}
// pack top-16 bits of two fp32 into one u32 (v_perm_b32)
__device__ __forceinline__ u32 pkhi(u32 u0, u32 u1) {
#if __has_builtin(__builtin_amdgcn_perm)
    return __builtin_amdgcn_perm(u1, u0, 0x07060302u);
#else
    return (u0 >> 16) | (u1 & 0xffff0000u);
#endif
}

// async global->LDS, 16B/lane; LDS dest = wave-uniform base (+lane*16 by HW)
__device__ __forceinline__ void gld16(const void* g, void* l) {
    __builtin_amdgcn_global_load_lds(
        (const __attribute__((address_space(1))) unsigned int*)g,
        (__attribute__((address_space(3))) unsigned int*)l, 16, 0, 0);
}

// ---------------------------------------------------------------------------
// BLOCKED hi/lo format (weights): each row of 1024 elems = 32 groups of 32;
// group t occupies 64 u16: [32 hi][32 lo]. Frag reads are ds_read_b128.
// ---------------------------------------------------------------------------

// Prep (wave-cooperative coalesced pack). Inputs are untouched (d_in stays
// read-only — qkv stages raw fp32 via global_load_lds, splits at frag-read):
//  y=0..2 : Wq/Wk/Wv -> blocked hi/lo into ws   (512 blocks, 8KB/block)
//  y=3    : f64-accurate RoPE table              (256 blocks)
//  y=4    : Wo -> blocked hi/lo into ws          (512 blocks)
__global__ __launch_bounds__(256) void prep_kernel(
    const float* __restrict__ Wq, const float* __restrict__ Wk,
    const float* __restrict__ Wv, const float* __restrict__ Wo,
    u16* __restrict__ wqb, u16* __restrict__ wkb, u16* __restrict__ wvb,
    u16* __restrict__ wob, float2* __restrict__ tab)
{
    const int y = blockIdx.y;
    if (y == 3) {
        if (blockIdx.x >= 256) return;
        const int e = blockIdx.x * 256 + threadIdx.x;   // 65536 = 2048 s x 32 i
        const int s = e >> 5, i = e & 31;
        const double th = exp(-(double)i * (9.210340371976184 / 32.0)); // ln(1e4)/32
        double sn, cs;
        sincos((double)s * th, &sn, &cs);
        tab[e] = make_float2((float)sn, (float)cs);
        return;
    }
    const float* src = (y == 0) ? Wq : (y == 1) ? Wk : (y == 2) ? Wv : Wo;
    u16* dst = (y == 0) ? wqb : (y == 1) ? wkb : (y == 2) ? wvb : wob;
    const int lane = threadIdx.x & 63;
    const int wv   = threadIdx.x >> 6;                  // wave 0..3
    const int g8   = lane >> 3;                         // group within KB
    const int l8   = lane & 7;
    for (int r = 0; r < 2; ++r) {                       // 4MB / 512 blocks = 8KB
        const size_t kb = (size_t)blockIdx.x * 8 + (size_t)r * 4 + wv;
        const float4 x4 = *(const float4*)(src + kb * 256 + lane * 4);
        __align__(8) u16 hb[4];
        __align__(8) u16 lb[4];
        const float xs[4] = {x4.x, x4.y, x4.z, x4.w};
        #pragma unroll
        for (int i = 0; i < 4; ++i) {
            const u32 h = f2bf(xs[i]);
            hb[i] = (u16)h;
            lb[i] = (u16)f2bf(xs[i] - bf2f(h));
        }
        u16* o = dst + kb * 512 + g8 * 64 + l8 * 4;
        *(uint2*)o        = *(const uint2*)hb;
        *(uint2*)(o + 32) = *(const uint2*)lb;
    }
}

// ---------------------------------------------------------------------------
// Merged Q/K/V projection, NI=8 (BM=128, BN=128, 2 heads/block), 2-phase
// schedule, 2 blocks/CU (64KB LDS). A = RAW fp32 input staged via
// global_load_lds (d_in read-only), source-address XOR pre-swizzle:
//   LDS[r][chunk j] = A[r][chunk j^(r&7)]  (chunk = 16B = 4 fp32)
// Frag read = 2x ds_read_b128 fp32 per mi; hi/lo split IN REGISTERS at read
// time (trunc-hi via v_perm + residual cvt_pk) — same LDS bytes as blocked
// bf16 hi/lo (fp32 tile = 16KB/buf), no ds_writes, no reg-staging latency.
// B (weights) = blocked hi/lo via gld16 as before.
// mode 0: RoPE(+scale)+hi/lo split -> [b][h][s][d] (Q/K), 2 heads/block
// mode 1: bf16-hi, LDS-transposed + key-quartet-permuted -> V^T (2 passes)
// ---------------------------------------------------------------------------
__global__ __launch_bounds__(256) void qkv_gemm_kernel(
    const float* __restrict__ query, const float* __restrict__ key,
    const float* __restrict__ value,
    const u16* __restrict__ Wqb, const u16* __restrict__ Wkb,
    const u16* __restrict__ Wvb,
    const float* __restrict__ bq, const float* __restrict__ bk,
    const float* __restrict__ bv, const float2* __restrict__ tab,
    u16* __restrict__ Qh, u16* __restrict__ Ql,
    u16* __restrict__ Kh, u16* __restrict__ Kl,
    u16* __restrict__ VTh)
{
    __shared__ u16 smem16[32768];       // 64 KB
    float* sAf = (float*)smem16;        // A fp32: 2 x 128 x 32  (32 KB)
    u16*   sB  = smem16 + 16384;        // B u16 : 2 x 128 x 64  (32 KB)

    const int z  = blockIdx.z;
    const float* Af   = (z == 0) ? query : (z == 1) ? key : value;
    const u16* Wb     = (z == 0) ? Wqb : (z == 1) ? Wkb : Wvb;
    const float* bias = (z == 0) ? bq : (z == 1) ? bk : bv;
    u16* Oh = (z == 0) ? Qh : (z == 1) ? Kh : VTh;
    u16* Ol = (z == 0) ? Ql : (z == 1) ? Kl : nullptr;
    const float rope_scale = (z == 0) ? 0.125f * LOG2E : 1.0f;
    const int mode = (z == 2) ? 1 : 0;

    const int tid   = threadIdx.x;
    const int w     = tid >> 6;
    const int lane  = tid & 63;
    const int lrow  = lane & 15;
    const int lquad = lane >> 4;

    // XCD-aware remap: 256 tiles/proj; per XCD 4 m-tiles x 8 n-tiles
    const int id   = blockIdx.x + 16 * blockIdx.y;  // 0..255
    const int xcd  = id & 7;
    const int jj   = id >> 3;                       // 0..31
    const int nblk = jj & 7;
    const int mblk = (xcd << 2) | (jj >> 3);        // 0..31
    const int n0   = nblk * 128;
    const int m0   = mblk * 128;

    // staging coords: 8-row slabs, 8 chunks of 16B per 128B row-slice
    const int srow8 = lane >> 3;
    const int sch   = (lane & 7) ^ srow8;

    // A frag offsets (u32 units): fp32 chunks (2*lquad)^(ra&7), (2*lquad+1)^(ra&7)
    int aoff0[2], aoff1[2];
    #pragma unroll
    for (int mi = 0; mi < 2; ++mi) {
        const int ra = w * 32 + mi * 16 + lrow;
        aoff0[mi] = ra * 32 + (((2 * lquad)     ^ (ra & 7)) << 2);
        aoff1[mi] = ra * 32 + (((2 * lquad + 1) ^ (ra & 7)) << 2);
    }
    // B frag offsets (u16 units): hi chunk = lquad, lo chunk = 4+lquad
    int boffh[8], boffl[8];
    #pragma unroll
    for (int ni = 0; ni < 8; ++ni) {
        const int rb = ni * 16 + lrow;
        boffh[ni] = rb * 64 + ((lquad ^ (rb & 7)) << 3);
        boffl[ni] = rb * 64 + (((lquad + 4) ^ (rb & 7)) << 3);
    }

    f32x4 acc[2][8] = {};

    // per tile: A 4 gld16/wave (raw fp32, pre-swizzled source),
    //           B 4 gld16/wave (blocked u16)
    auto stage = [&](int t) {
        const int h = t & 1;
        #pragma unroll
        for (int i = 0; i < 4; ++i) {
            const int slab = w * 4 + i;
            const int row  = slab * 8 + srow8;
            gld16(Af + (size_t)(m0 + row) * 1024 + t * 32 + sch * 4,
                  sAf + h * 4096 + slab * 256);
            gld16(Wb + (size_t)(n0 + row) * 2048 + t * 64 + sch * 8,
                  sB + h * 8192 + slab * 512);
        }
    };

    // fp32x8 -> (hi bfrag, lo bfrag): trunc-hi via v_perm + residual cvt_pk
    auto cvtAB = [&](const f32x4 a, const f32x4 b, bfrag& hi8, bfrag& lo8) {
        const u32 u0 = __float_as_uint(a[0]), u1 = __float_as_uint(a[1]);
        const u32 u2 = __float_as_uint(a[2]), u3 = __float_as_uint(a[3]);
        const u32 u4 = __float_as_uint(b[0]), u5 = __float_as_uint(b[1]);
        const u32 u6 = __float_as_uint(b[2]), u7 = __float_as_uint(b[3]);
        fragu fh, fl;
        fh.u[0] = pkhi(u0, u1); fh.u[1] = pkhi(u2, u3);
        fh.u[2] = pkhi(u4, u5); fh.u[3] = pkhi(u6, u7);
        fl.u[0] = pk2bf(a[0] - __uint_as_float(u0 & 0xffff0000u),
                        a[1] - __uint_as_float(u1 & 0xffff0000u));
        fl.u[1] = pk2bf(a[2] - __uint_as_float(u2 & 0xffff0000u),
                        a[3] - __uint_as_float(u3 & 0xffff0000u));
        fl.u[2] = pk2bf(b[0] - __uint_as_float(u4 & 0xffff0000u),
                        b[1] - __uint_as_float(u5 & 0xffff0000u));
        fl.u[3] = pk2bf(b[2] - __uint_as_float(u6 & 0xffff0000u),
                        b[3] - __uint_as_float(u7 & 0xffff0000u));
        hi8 = fh.f; lo8 = fl.f;
    };

    stage(0);
    for (int t = 0; t < 32; ++t) {
        __syncthreads();                 // buf t ready (vmcnt drained)
        if (t < 31) stage(t + 1);
        const int h = t & 1;
        const float* sAh_ = sAf + h * 4096;
        const u16*   sBh_ = sB + h * 8192;

        bfrag ah[2], al[2], bh[8], bl[8];
        #pragma unroll
        for (int mi = 0; mi < 2; ++mi) {
            const f32x4 a0 = *(const f32x4*)&sAh_[aoff0[mi]];
            const f32x4 a1 = *(const f32x4*)&sAh_[aoff1[mi]];
            cvtAB(a0, a1, ah[mi], al[mi]);
        }
        #pragma unroll
        for (int ni = 0; ni < 8; ++ni) {
            bh[ni] = *(const bfrag*)&sBh_[boffh[ni]];
            bl[ni] = *(const bfrag*)&sBh_[boffl[ni]];
        }

        #pragma unroll
        for (int mi = 0; mi < 2; ++mi)
            #pragma unroll
            for (int ni = 0; ni < 8; ++ni) {
                acc[mi][ni] = __builtin_amdgcn_mfma_f32_16x16x32_bf16(ah[mi], bh[ni], acc[mi][ni], 0, 0, 0);
                acc[mi][ni] = __builtin_amdgcn_mfma_f32_16x16x32_bf16(ah[mi], bl[ni], acc[mi][ni], 0, 0, 0);
                acc[mi][ni] = __builtin_amdgcn_mfma_f32_16x16x32_bf16(al[mi], bh[ni], acc[mi][ni], 0, 0, 0);
            }
    }

    float bn[8];
    #pragma unroll
    for (int ni = 0; ni < 8; ++ni) bn[ni] = bias[n0 + ni * 16 + lrow];

    if (mode == 0) {
        // RoPE + hi/lo split write; block spans 2 heads (64 cols each)
        #pragma unroll
        for (int mi = 0; mi < 2; ++mi)
            #pragma unroll
            for (int r = 0; r < 4; ++r) {
                const int mrow = w * 32 + mi * 16 + lquad * 4 + r;
                const int m  = m0 + mrow;
                const int bb = m & 1;
                const int sg = m >> 1;
                #pragma unroll
                for (int hh = 0; hh < 2; ++hh) {
                    const int head = nblk * 2 + hh;
                    const size_t ob = (((size_t)(bb * NHEADS + head) * SEQ) + sg) * HDIM;
                    #pragma unroll
                    for (int ni = 0; ni < 2; ++ni) {
                        const int i = ni * 16 + lrow;
                        const float2 sc = tab[(size_t)sg * 32 + i];
                        const float x1 = acc[mi][hh * 4 + ni][r]     + bn[hh * 4 + ni];
                        const float x2 = acc[mi][hh * 4 + ni + 2][r] + bn[hh * 4 + ni + 2];
                        // reference quirk: o2 = x1*sin - x2*cos
                        const float o1 = (x1 * sc.y - x2 * sc.x) * rope_scale;
                        const float o2 = (x1 * sc.x - x2 * sc.y) * rope_scale;
                        const u32 h1 = f2bf(o1);
                        const u32 h2 = f2bf(o2);
                        Oh[ob + i]      = (u16)h1;  Ol[ob + i]      = (u16)f2bf(o1 - bf2f(h1));
                        Oh[ob + i + 32] = (u16)h2;  Ol[ob + i + 32] = (u16)f2bf(o2 - bf2f(h2));
                    }
                }
            }
        return;
    }
    // mode 1: bf16-hi V^T, transposed via LDS (stride 65), key-quartet
    // permuted; two passes (one batch parity each), vb 33KB <= 64KB.
    __syncthreads();
    u32* vb = (u32*)smem16;
    for (int p = 0; p < 2; ++p) {
        if (p) __syncthreads();
        #pragma unroll
        for (int mi = 0; mi < 2; ++mi)
            #pragma unroll
            for (int r = 0; r < 4; ++r) {
                const int mrow = w * 32 + mi * 16 + lquad * 4 + r;
                const int bb = mrow & 1;
                const int sl = mrow >> 1;
                if (bb == p) {
                    #pragma unroll
                    for (int ni = 0; ni < 8; ++ni) {
                        const int d = ni * 16 + lrow;
                        vb[d * 65 + sl] = f2bf(acc[mi][ni][r] + bn[ni]);
                    }
                }
            }
        __syncthreads();
        #pragma unroll
        for (int rep = 0; rep < 4; ++rep) {
            const int c  = rep * 256 + tid;      // 1024 chunks per pass
            const int dc = c >> 3;               // 0..127
            const int s8 = c & 7;
            __align__(8) u16 hb[8];
            #pragma unroll
            for (int j = 0; j < 8; ++j)
                hb[j] = (u16)vb[dc * 65 + s8 * 8 + j];
            const int head = nblk * 2 + (dc >> 6);
            const int dd   = dc & 63;
            const size_t orow = ((size_t)(p * NHEADS + head) * HDIM + dd) * SEQ + (m0 >> 1);
            const int blk16 = (s8 >> 1) * 16;
            const int off   = (s8 & 1) * 4;
            *(uint2*)&Oh[orow + blk16 + off]     = *(const uint2*)&hb[0];
            *(uint2*)&Oh[orow + blk16 + 8 + off] = *(const uint2*)&hb[4];
        }
    }
}

// ---------------------------------------------------------------------------
// 2-phase GEMM body for out_gemm (blocked A via gld16): BM=128, BN=NI*16,
// mode 2 fp32 row-major output. Unchanged control.
// ---------------------------------------------------------------------------
template <int NI>
__device__ __forceinline__ void gemm_body(
    int id,
    const u16* __restrict__ Ab, const u16* __restrict__ Wb,
    const float* __restrict__ bias, float* __restrict__ Of,
    u16* smem16)
{
    u16* sA = smem16;               // 2 halves x 128 rows x 64 u16
    u16* sB = smem16 + 16384;       // 2 halves x (NI*16) rows x 64 u16

    const int tid   = threadIdx.x;
    const int w     = tid >> 6;
    const int lane  = tid & 63;
    const int lrow  = lane & 15;
    const int lquad = lane >> 4;

    const int NBLK = 1024 / (NI * 16);
    const int xcd  = id & 7;
    const int jj   = id >> 3;
    const int nblk = jj & (NBLK - 1);
    const int mblk = (xcd << 2) | (jj / NBLK);
    const int n0   = nblk * NI * 16;
    const int m0   = mblk * 128;

    const int srow8 = lane >> 3;
    const int sch   = (lane & 7) ^ srow8;

    int aoffh[2], aoffl[2], boffh[NI], boffl[NI];
    #pragma unroll
    for (int mi = 0; mi < 2; ++mi) {
        const int ra = w * 32 + mi * 16 + lrow;
        aoffh[mi] = ra * 64 + ((lquad ^ (ra & 7)) << 3);
        aoffl[mi] = ra * 64 + (((lquad + 4) ^ (ra & 7)) << 3);
    }
    #pragma unroll
    for (int ni = 0; ni < NI; ++ni) {
        const int rb = ni * 16 + lrow;
        boffh[ni] = rb * 64 + ((lquad ^ (rb & 7)) << 3);
        boffl[ni] = rb * 64 + (((lquad + 4) ^ (rb & 7)) << 3);
    }

    f32x4 acc[2][NI] = {};

    auto stage = [&](int t) {
        const int h = t & 1;
        #pragma unroll
        for (int i = 0; i < 4; ++i) {
            const int slab = w * 4 + i;
            const int row  = slab * 8 + srow8;
            gld16(Ab + (size_t)(m0 + row) * 2048 + t * 64 + sch * 8,
                  sA + h * 8192 + slab * 512);
        }
        #pragma unroll
        for (int i = 0; i < NI / 2; ++i) {
            const int slab = w * (NI / 2) + i;
            const int row  = slab * 8 + srow8;
            gld16(Wb + (size_t)(n0 + row) * 2048 + t * 64 + sch * 8,
                  sB + h * (NI * 1024) + slab * 512);
        }
    };

    stage(0);
    for (int t = 0; t < 32; ++t) {
        __syncthreads();
        if (t < 31) stage(t + 1);
        const int h = t & 1;
        const u16* sAh_ = sA + h * 8192;
        const u16* sBh_ = sB + h * (NI * 1024);

        bfrag ah[2], al[2], bh[NI], bl[NI];
        #pragma unroll
        for (int mi = 0; mi < 2; ++mi) {
            ah[mi] = *(const bfrag*)&sAh_[aoffh[mi]];
            al[mi] = *(const bfrag*)&sAh_[aoffl[mi]];
        }
        #pragma unroll
        for (int ni = 0; ni < NI; ++ni) {
            bh[ni] = *(const bfrag*)&sBh_[boffh[ni]];
            bl[ni] = *(const bfrag*)&sBh_[boffl[ni]];
        }

        #pragma unroll
        for (int mi = 0; mi < 2; ++mi)
            #pragma unroll
            for (int ni = 0; ni < NI; ++ni) {
                acc[mi][ni] = __builtin_amdgcn_mfma_f32_16x16x32_bf16(ah[mi], bh[ni], acc[mi][ni], 0, 0, 0);
                acc[mi][ni] = __builtin_amdgcn_mfma_f32_16x16x32_bf16(ah[mi], bl[ni], acc[mi][ni], 0, 0, 0);
                acc[mi][ni] = __builtin_amdgcn_mfma_f32_16x16x32_bf16(al[mi], bh[ni], acc[mi][ni], 0, 0, 0);
            }
    }

    float bn[NI];
    #pragma unroll
    for (int ni = 0; ni < NI; ++ni) bn[ni] = bias[n0 + ni * 16 + lrow];

    #pragma unroll
    for (int mi = 0; mi < 2; ++mi)
        #pragma unroll
        for (int r = 0; r < 4; ++r) {
            const int m = m0 + w * 32 + mi * 16 + lquad * 4 + r;
            #pragma unroll
            for (int ni = 0; ni < NI; ++ni)
                Of[(size_t)m * 1024 + n0 + ni * 16 + lrow] = acc[mi][ni][r] + bn[ni];
        }
}

// Final projection: A = attn output (blocked). NI=4 (BN=64, grid 512,
// 48KB LDS, 3 blocks/CU). Unchanged control.
__global__ __launch_bounds__(256) void out_gemm_kernel(
    const u16* __restrict__ Ab, const u16* __restrict__ Wb,
    const float* __restrict__ bias, float* __restrict__ Of)
{
    __shared__ u16 smem16[24576];                 // 48 KB
    const int id = blockIdx.x + 16 * blockIdx.y;
    gemm_body<4>(id, Ab, Wb, bias, Of, smem16);
}

// ---------------------------------------------------------------------------
// MFMA flash attention (non-split): 32x32x16, no-max softmax (exp2, Q
// pre-scaled by log2e/8), S^T/O^T form, double-buffered K/V tiles,
// register-P, permuted V^T (hi-only). Unchanged control.
// Block = 256 threads (4 waves) = 128 q-rows; grid 512; LDS 48 KB.
// ---------------------------------------------------------------------------
__global__ __launch_bounds__(256) void attn_mfma_kernel(
    const u16* __restrict__ Qh, const u16* __restrict__ Ql,
    const u16* __restrict__ Kh, const u16* __restrict__ Kl,
    const u16* __restrict__ Vh,
    u16* __restrict__ AOb)
{
    __shared__ u16 sKh[8192], sKl[8192];   // [buf][key][dh] swizzled
    __shared__ u16 sVh[8192];              // [buf][dh][key'] swizzled (permuted)

    const int tid  = threadIdx.x;
    const int w    = tid >> 6;             // 0..3
    const int lane = tid & 63;
    const int l31  = lane & 31;
    const int g    = lane >> 5;

    const int id = blockIdx.x + 16 * blockIdx.y;   // 0..511
    const int jj = id >> 3;                        // 0..63
    const int bh = ((id & 7) << 2) | (jj >> 4);
    const int qt = jj & 15;

    const size_t qg = ((size_t)bh * SEQ + qt * 128 + w * 32 + l31) * HDIM + g * 8;
    bfrag qfh[4], qfl[4];
    #pragma unroll
    for (int ks = 0; ks < 4; ++ks) {
        qfh[ks] = *(const bfrag*)&Qh[qg + ks * 16];
        qfl[ks] = *(const bfrag*)&Ql[qg + ks * 16];
    }

    const int srow   = lane >> 3;
    const int schunk = (lane & 7) ^ srow;
    const u16* gsrc = nullptr; u16* lbase = nullptr; size_t istep = 0, ktstep = 0;
    if (w == 0) {
        gsrc = Kh + ((size_t)bh * SEQ + srow) * HDIM + schunk * 8;
        istep = 8 * 64; ktstep = 64 * 64; lbase = sKh;
    } else if (w == 1) {
        gsrc = Kl + ((size_t)bh * SEQ + srow) * HDIM + schunk * 8;
        istep = 8 * 64; ktstep = 64 * 64; lbase = sKl;
    } else if (w == 2) {
        gsrc = Vh + ((size_t)bh * HDIM + srow) * SEQ + schunk * 8;
        istep = 8 * SEQ; ktstep = 64; lbase = sVh;
    }

    int koff[2][4];
    #pragma unroll
    for (int a = 0; a < 2; ++a) {
        const int row = a * 32 + l31;
        #pragma unroll
        for (int c = 0; c < 4; ++c)
            koff[a][c] = row * 64 + (((c * 2 + g) ^ (row & 7)) << 3);
    }

    f32x16 accO[2] = {};
    float l_loc = 0.0f;

    auto stage = [&](int kt) {
        if (w < 3) {
            const u16* gp = gsrc + (size_t)kt * ktstep;
            u16* dst = lbase + (kt & 1) * 4096;
            #pragma unroll
            for (int i = 0; i < 8; ++i)
                gld16(gp + (size_t)i * istep, dst + i * 512);
        }
    };

    stage(0);
    for (int kt = 0; kt < SEQ / 64; ++kt) {
        __syncthreads();                     // tile kt ready (vmcnt drained)
        if (kt < SEQ / 64 - 1) stage(kt + 1);
        const int po = (kt & 1) * 4096;

        // ---- S^T = K Q^T (Q pre-scaled by log2e/8) : lane=q, regs=keys ----
        f32x16 accS[2] = {};
        #pragma unroll
        for (int kg = 0; kg < 2; ++kg)
            #pragma unroll
            for (int ks = 0; ks < 4; ++ks) {
                const bfrag kh_ = *(const bfrag*)&sKh[po + koff[kg][ks]];
                const bfrag kl_ = *(const bfrag*)&sKl[po + koff[kg][ks]];
                accS[kg] = __builtin_amdgcn_mfma_f32_32x32x16_bf16(kh_, qfh[ks], accS[kg], 0, 0, 0);
                accS[kg] = __builtin_amdgcn_mfma_f32_32x32x16_bf16(kh_, qfl[ks], accS[kg], 0, 0, 0);
                accS[kg] = __builtin_amdgcn_mfma_f32_32x32x16_bf16(kl_, qfh[ks], accS[kg], 0, 0, 0);
            }

        // ---- p = exp2(s') in registers (lane=q, reg=key) ----
        float pv[2][16];
        #pragma unroll
        for (int kg = 0; kg < 2; ++kg)
            #pragma unroll
            for (int r = 0; r < 16; ++r) {
                const float p = fexp2(accS[kg][r]);
                pv[kg][r] = p;
                l_loc += p;
            }

        // ---- O^T += Vh^T P^T (no exchange: permuted V^T; hi-only) ----
        #pragma unroll
        for (int kp = 0; kp < 4; ++kp) {
            const int kg = kp >> 1;
            const int t8 = (kp & 1) * 8;
            fragu ph;
            #pragma unroll
            for (int j2 = 0; j2 < 4; ++j2)
                ph.u[j2] = pk2bf(pv[kg][t8 + 2 * j2], pv[kg][t8 + 2 * j2 + 1]);
            #pragma unroll
            for (int dt = 0; dt < 2; ++dt) {
                const bfrag vh = *(const bfrag*)&sVh[po + koff[dt][kp]];
                accO[dt] = __builtin_amdgcn_mfma_f32_32x32x16_bf16(vh, ph.f, accO[dt], 0, 0, 0);
            }
        }
    }

    // ---- l: combine complementary g-halves; write BLOCKED hi/lo output ----
    const float inv = 1.0f / (l_loc + __shfl_xor(l_loc, 32));

    const int b = bh >> 4;
    const int h = bh & 15;
    const int sg = qt * 128 + w * 32 + l31;
    const int rm = sg * BATCH + b;                 // output row (0..4095)
    #pragma unroll
    for (int dt = 0; dt < 2; ++dt)
        #pragma unroll
        for (int rq = 0; rq < 4; ++rq) {
            const int j0 = 8 * rq + 4 * g;         // pos within 32-group
            const int t  = h * 2 + dt;             // group index
            __align__(8) u16 hb[4];
            __align__(8) u16 lb[4];
            #pragma unroll
            for (int i2 = 0; i2 < 4; ++i2) {
                const float v = accO[dt][rq * 4 + i2] * inv;
                const u32 hh = f2bf(v);
                hb[i2] = (u16)hh;
                lb[i2] = (u16)f2bf(v - bf2f(hh));
            }
            u16* o = AOb + (size_t)rm * 2048 + t * 64 + j0;
            *(uint2*)o        = *(const uint2*)hb;
            *(uint2*)(o + 32) = *(const uint2*)lb;
        }
}

// ---------------------------------------------------------------------------
extern "C" void kernel_launch(void* const* d_in, const int* in_sizes, int n_in,
                              void* d_out, int out_size, void* d_ws, size_t ws_size,
                              hipStream_t stream)
{
    const float* query = (const float*)d_in[0];   // READ-ONLY (never written)
    const float* key   = (const float*)d_in[1];
    const float* value = (const float*)d_in[2];
    const float* Wq    = (const float*)d_in[3];
    const float* bq    = (const float*)d_in[4];
    const float* Wk    = (const float*)d_in[5];
    const float* bk    = (const float*)d_in[6];
    const float* Wv    = (const float*)d_in[7];
    const float* bv    = (const float*)d_in[8];
    const float* Wo    = (const float*)d_in[9];
    const float* bo    = (const float*)d_in[10];
    float* out = (float*)d_out;

    // 64 MB workspace, time-multiplexed (MB offsets):
    //  Wqb [0,4) Wkb [4,8) Wvb [8,12) tab [12,12.5)  -- dead after qkv
    //  Qh [16,24) Ql [24,32) Kh [32,40) Kl [40,48) VTh [48,56)
    //  Wob [56,60)          (written in prep, read by out_gemm — never aliased)
    //  AOb blocked [0,16)   (attn output; W-packs + tab dead after qkv)
    char* wsb = (char*)d_ws;
    const size_t MB = 1024 * 1024;
    u16* Wqb = (u16*)(wsb + 0 * MB);
    u16* Wkb = (u16*)(wsb + 4 * MB);
    u16* Wvb = (u16*)(wsb + 8 * MB);
    float2* tab = (float2*)(wsb + 12 * MB);
    u16* Qh  = (u16*)(wsb + 16 * MB); u16* Ql  = (u16*)(wsb + 24 * MB);
    u16* Kh  = (u16*)(wsb + 32 * MB); u16* Kl  = (u16*)(wsb + 40 * MB);
    u16* VTh = (u16*)(wsb + 48 * MB);
    u16* Wob = (u16*)(wsb + 56 * MB);
    u16* AOb = (u16*)(wsb + 0 * MB);

    // pack weights (incl. Wo) + RoPE table (inputs untouched)
    prep_kernel<<<dim3(512, 5), 256, 0, stream>>>(
        Wq, Wk, Wv, Wo, Wqb, Wkb, Wvb, Wob, tab);
    // merged Q/K/V projections (+RoPE for Q/K; Q pre-scaled; V writes V^T hi);
    // A = raw fp32 via global_load_lds, hi/lo split at frag-read
    qkv_gemm_kernel<<<dim3(16, 16, 3), 256, 0, stream>>>(
        query, key, value,
        Wqb, Wkb, Wvb, bq, bk, bv, tab, Qh, Ql, Kh, Kl, VTh);
    // attention -> blocked hi/lo (S,B,D)
    attn_mfma_kernel<<<dim3(16, 32), 256, 0, stream>>>(
        Qh, Ql, Kh, Kl, VTh, AOb);
    // output projection (NI=4: BN=64, 512 blocks)
    out_gemm_kernel<<<dim3(16, 32), 256, 0, stream>>>(AOb, Wob, bo, out);
}

// Round 9
// 280.965 us; speedup vs baseline: 1.1246x; 1.0529x over previous
//
#include <hip/hip_runtime.h>
#include <hip/hip_bf16.h>
#include <hip/hip_fp16.h>

// Problem constants
#define DMODEL 1024
#define NHEADS 16
#define HDIM   64
#define SEQ    2048
#define BATCH  2
#define MROWS  (SEQ*BATCH)   // 4096

typedef unsigned int u32;
typedef unsigned short u16;
typedef __attribute__((ext_vector_type(8))) short bfrag;      // 8x16b (bf16 frag)
typedef __attribute__((ext_vector_type(8))) _Float16 hfrag;   // 8x f16 frag
typedef __attribute__((ext_vector_type(4))) float f32x4;      // 16x16 C/D frag
typedef __attribute__((ext_vector_type(16))) float f32x16;    // 32x32 C/D frag
typedef union { u32 u[4]; bfrag f; } fragu;
typedef union { u32 u[4]; hfrag f; } fragh;

#define LOG2E 1.44269504088896341f

// bf16 split helpers (RTN-even hi). x ~= hi + lo
__device__ __forceinline__ u32 f2bf(float x) {
    unsigned u = __float_as_uint(x);
    return (u + 0x7fffu + ((u >> 16) & 1u)) >> 16;
}
__device__ __forceinline__ float bf2f(u32 h) {
    return __uint_as_float(h << 16);
}
// packed 2xf32 -> 2xbf16 (v_cvt_pk_bf16_f32 on gfx950), a=low, b=high
__device__ __forceinline__ u32 pk2bf(float a, float b) {
    __hip_bfloat162 t = __float22bfloat162_rn(make_float2(a, b));
    u32 r;
    __builtin_memcpy(&r, &t, 4);
    return r;
}
// packed 2xf32 -> 2xf16 (v_cvt_pkrtz_f16_f32), a=low, b=high
__device__ __forceinline__ u32 pkf16(float a, float b) {
#if __has_builtin(__builtin_amdgcn_cvt_pkrtz)
    __fp16 __attribute__((ext_vector_type(2))) t = __builtin_amdgcn_cvt_pkrtz(a, b);
    u32 r;
    __builtin_memcpy(&r, &t, 4);
    return r;
#else
    __half2 t = __floats2half2_rn(a, b);
    u32 r;
    __builtin_memcpy(&r, &t, 4);
    return r;
#endif
}
__device__ __forceinline__ float fexp2(float x) {
#if __has_builtin(__builtin_amdgcn_exp2f)
    return __builtin_amdgcn_exp2f(x);
#else
    return exp2f(x);
#endif
}
// pack top-16 bits of two fp32 into one u32 (v_perm_b32)
__device__ __forceinline__ u32 pkhi(u32 u0, u32 u1) {
#if __has_builtin(__builtin_amdgcn_perm)
    return __builtin_amdgcn_perm(u1, u0, 0x07060302u);
#else
    return (u0 >> 16) | (u1 & 0xffff0000u);
#endif
}

// async global->LDS, 16B/lane; LDS dest = wave-uniform base (+lane*16 by HW)
__device__ __forceinline__ void gld16(const void* g, void* l) {
    __builtin_amdgcn_global_load_lds(
        (const __attribute__((address_space(1))) unsigned int*)g,
        (__attribute__((address_space(3))) unsigned int*)l, 16, 0, 0);
}

// ---------------------------------------------------------------------------
// BLOCKED hi/lo format (weights): each row of 1024 elems = 32 groups of 32;
// group t occupies 64 u16: [32 hi][32 lo]. Frag reads are ds_read_b128.
// For Wq/Wk/Wv the hi half is F16 (RN) and lo is BF16 residual (fp32 exponent
// range -> no denormal flush); qkv then needs only 2 MFMA per frag pair:
//   f16_mfma(A_f16, Wh_f16) + bf16_mfma(A_bf16hi, Wl_bf16)
// For Wo the pack stays bf16/bf16 (out_gemm unchanged, 3-MFMA).
// ---------------------------------------------------------------------------

// Prep (wave-cooperative coalesced pack). Inputs untouched (d_in read-only):
//  y=0..2 : Wq/Wk/Wv -> blocked f16-hi/bf16-lo     (512 blocks, 8KB/block)
//  y=3    : f64-accurate RoPE table                 (256 blocks)
//  y=4    : Wo -> blocked bf16 hi/lo                (512 blocks)
__global__ __launch_bounds__(256) void prep_kernel(
    const float* __restrict__ Wq, const float* __restrict__ Wk,
    const float* __restrict__ Wv, const float* __restrict__ Wo,
    u16* __restrict__ wqb, u16* __restrict__ wkb, u16* __restrict__ wvb,
    u16* __restrict__ wob, float2* __restrict__ tab)
{
    const int y = blockIdx.y;
    if (y == 3) {
        if (blockIdx.x >= 256) return;
        const int e = blockIdx.x * 256 + threadIdx.x;   // 65536 = 2048 s x 32 i
        const int s = e >> 5, i = e & 31;
        const double th = exp(-(double)i * (9.210340371976184 / 32.0)); // ln(1e4)/32
        double sn, cs;
        sincos((double)s * th, &sn, &cs);
        tab[e] = make_float2((float)sn, (float)cs);
        return;
    }
    const float* src = (y == 0) ? Wq : (y == 1) ? Wk : (y == 2) ? Wv : Wo;
    u16* dst = (y == 0) ? wqb : (y == 1) ? wkb : (y == 2) ? wvb : wob;
    const bool f16hi = (y < 3);
    const int lane = threadIdx.x & 63;
    const int wv   = threadIdx.x >> 6;                  // wave 0..3
    const int g8   = lane >> 3;                         // group within KB
    const int l8   = lane & 7;
    for (int r = 0; r < 2; ++r) {                       // 4MB / 512 blocks = 8KB
        const size_t kb = (size_t)blockIdx.x * 8 + (size_t)r * 4 + wv;
        const float4 x4 = *(const float4*)(src + kb * 256 + lane * 4);
        __align__(8) u16 hb[4];
        __align__(8) u16 lb[4];
        const float xs[4] = {x4.x, x4.y, x4.z, x4.w};
        #pragma unroll
        for (int i = 0; i < 4; ++i) {
            if (f16hi) {
                const __half hh = __float2half(xs[i]);           // RN f16
                hb[i] = __half_as_ushort(hh);
                lb[i] = (u16)f2bf(xs[i] - __half2float(hh));     // bf16 residual
            } else {
                const u32 h = f2bf(xs[i]);
                hb[i] = (u16)h;
                lb[i] = (u16)f2bf(xs[i] - bf2f(h));
            }
        }
        u16* o = dst + kb * 512 + g8 * 64 + l8 * 4;
        *(uint2*)o        = *(const uint2*)hb;
        *(uint2*)(o + 32) = *(const uint2*)lb;
    }
}

// ---------------------------------------------------------------------------
// Merged Q/K/V projection, NI=8 (BM=128, BN=128, 2 heads/block), 2-phase
// schedule, 2 blocks/CU (64KB LDS). A = RAW fp32 input staged via
// global_load_lds (d_in read-only), source-address XOR pre-swizzle.
// Frag read = 2x ds_read_b128 fp32 per mi; A converted IN REGISTERS to
//   a16 (single f16 via v_cvt_pkrtz) and abf (bf16-hi via v_perm).
// W = blocked f16-hi/bf16-lo. 2 MFMA per (mi,ni):
//   mfma_f16(a16, Wh) + mfma_bf16(abf, Wl)   [32 MFMA/t/wave, was 48]
// Error: A-f16 ~2^-12, W captured to ~2^-19 -> ~2e-4 per proj elem, well
// under the 2^-9 absmax budget (dominated by attn's P-bf16 path).
// mode 0: RoPE(+scale)+hi/lo split -> [b][h][s][d] (Q/K), 2 heads/block
// mode 1: bf16-hi, LDS-transposed + key-quartet-permuted -> V^T (2 passes)
// ---------------------------------------------------------------------------
__global__ __launch_bounds__(256) void qkv_gemm_kernel(
    const float* __restrict__ query, const float* __restrict__ key,
    const float* __restrict__ value,
    const u16* __restrict__ Wqb, const u16* __restrict__ Wkb,
    const u16* __restrict__ Wvb,
    const float* __restrict__ bq, const float* __restrict__ bk,
    const float* __restrict__ bv, const float2* __restrict__ tab,
    u16* __restrict__ Qh, u16* __restrict__ Ql,
    u16* __restrict__ Kh, u16* __restrict__ Kl,
    u16* __restrict__ VTh)
{
    __shared__ u16 smem16[32768];       // 64 KB
    float* sAf = (float*)smem16;        // A fp32: 2 x 128 x 32  (32 KB)
    u16*   sB  = smem16 + 16384;        // B u16 : 2 x 128 x 64  (32 KB)

    const int z  = blockIdx.z;
    const float* Af   = (z == 0) ? query : (z == 1) ? key : value;
    const u16* Wb     = (z == 0) ? Wqb : (z == 1) ? Wkb : Wvb;
    const float* bias = (z == 0) ? bq : (z == 1) ? bk : bv;
    u16* Oh = (z == 0) ? Qh : (z == 1) ? Kh : VTh;
    u16* Ol = (z == 0) ? Ql : (z == 1) ? Kl : nullptr;
    const float rope_scale = (z == 0) ? 0.125f * LOG2E : 1.0f;
    const int mode = (z == 2) ? 1 : 0;

    const int tid   = threadIdx.x;
    const int w     = tid >> 6;
    const int lane  = tid & 63;
    const int lrow  = lane & 15;
    const int lquad = lane >> 4;

    // XCD-aware remap: 256 tiles/proj; per XCD 4 m-tiles x 8 n-tiles
    const int id   = blockIdx.x + 16 * blockIdx.y;  // 0..255
    const int xcd  = id & 7;
    const int jj   = id >> 3;                       // 0..31
    const int nblk = jj & 7;
    const int mblk = (xcd << 2) | (jj >> 3);        // 0..31
    const int n0   = nblk * 128;
    const int m0   = mblk * 128;

    // staging coords: 8-row slabs, 8 chunks of 16B per 128B row-slice
    const int srow8 = lane >> 3;
    const int sch   = (lane & 7) ^ srow8;

    // A frag offsets (u32 units): fp32 chunks (2*lquad)^(ra&7), (2*lquad+1)^(ra&7)
    int aoff0[2], aoff1[2];
    #pragma unroll
    for (int mi = 0; mi < 2; ++mi) {
        const int ra = w * 32 + mi * 16 + lrow;
        aoff0[mi] = ra * 32 + (((2 * lquad)     ^ (ra & 7)) << 2);
        aoff1[mi] = ra * 32 + (((2 * lquad + 1) ^ (ra & 7)) << 2);
    }
    // B frag offsets (u16 units): hi chunk = lquad, lo chunk = 4+lquad
    int boffh[8], boffl[8];
    #pragma unroll
    for (int ni = 0; ni < 8; ++ni) {
        const int rb = ni * 16 + lrow;
        boffh[ni] = rb * 64 + ((lquad ^ (rb & 7)) << 3);
        boffl[ni] = rb * 64 + (((lquad + 4) ^ (rb & 7)) << 3);
    }

    f32x4 acc[2][8] = {};

    // per tile: A 4 gld16/wave (raw fp32, pre-swizzled source),
    //           B 4 gld16/wave (blocked u16)
    auto stage = [&](int t) {
        const int h = t & 1;
        #pragma unroll
        for (int i = 0; i < 4; ++i) {
            const int slab = w * 4 + i;
            const int row  = slab * 8 + srow8;
            gld16(Af + (size_t)(m0 + row) * 1024 + t * 32 + sch * 4,
                  sAf + h * 4096 + slab * 256);
            gld16(Wb + (size_t)(n0 + row) * 2048 + t * 64 + sch * 8,
                  sB + h * 8192 + slab * 512);
        }
    };

    // fp32x8 -> (f16 frag, bf16-hi frag)
    auto cvtA = [&](const f32x4 a, const f32x4 b, hfrag& a16, bfrag& abf) {
        fragh fh;
        fh.u[0] = pkf16(a[0], a[1]); fh.u[1] = pkf16(a[2], a[3]);
        fh.u[2] = pkf16(b[0], b[1]); fh.u[3] = pkf16(b[2], b[3]);
        fragu fb;
        fb.u[0] = pkhi(__float_as_uint(a[0]), __float_as_uint(a[1]));
        fb.u[1] = pkhi(__float_as_uint(a[2]), __float_as_uint(a[3]));
        fb.u[2] = pkhi(__float_as_uint(b[0]), __float_as_uint(b[1]));
        fb.u[3] = pkhi(__float_as_uint(b[2]), __float_as_uint(b[3]));
        a16 = fh.f; abf = fb.f;
    };

    stage(0);
    for (int t = 0; t < 32; ++t) {
        __syncthreads();                 // buf t ready (vmcnt drained)
        if (t < 31) stage(t + 1);
        const int h = t & 1;
        const float* sAh_ = sAf + h * 4096;
        const u16*   sBh_ = sB + h * 8192;

        hfrag a16[2];
        bfrag abf[2], bl[8];
        hfrag bh16[8];
        #pragma unroll
        for (int mi = 0; mi < 2; ++mi) {
            const f32x4 a0 = *(const f32x4*)&sAh_[aoff0[mi]];
            const f32x4 a1 = *(const f32x4*)&sAh_[aoff1[mi]];
            cvtA(a0, a1, a16[mi], abf[mi]);
        }
        #pragma unroll
        for (int ni = 0; ni < 8; ++ni) {
            fragh tmp;
            fragu raw;
            raw.f = *(const bfrag*)&sBh_[boffh[ni]];
            tmp.u[0] = raw.u[0]; tmp.u[1] = raw.u[1];
            tmp.u[2] = raw.u[2]; tmp.u[3] = raw.u[3];
            bh16[ni] = tmp.f;
            bl[ni]   = *(const bfrag*)&sBh_[boffl[ni]];
        }

        #pragma unroll
        for (int mi = 0; mi < 2; ++mi)
            #pragma unroll
            for (int ni = 0; ni < 8; ++ni) {
                acc[mi][ni] = __builtin_amdgcn_mfma_f32_16x16x32_f16(a16[mi], bh16[ni], acc[mi][ni], 0, 0, 0);
                acc[mi][ni] = __builtin_amdgcn_mfma_f32_16x16x32_bf16(abf[mi], bl[ni], acc[mi][ni], 0, 0, 0);
            }
    }

    float bn[8];
    #pragma unroll
    for (int ni = 0; ni < 8; ++ni) bn[ni] = bias[n0 + ni * 16 + lrow];

    if (mode == 0) {
        // RoPE + hi/lo split write; block spans 2 heads (64 cols each)
        #pragma unroll
        for (int mi = 0; mi < 2; ++mi)
            #pragma unroll
            for (int r = 0; r < 4; ++r) {
                const int mrow = w * 32 + mi * 16 + lquad * 4 + r;
                const int m  = m0 + mrow;
                const int bb = m & 1;
                const int sg = m >> 1;
                #pragma unroll
                for (int hh = 0; hh < 2; ++hh) {
                    const int head = nblk * 2 + hh;
                    const size_t ob = (((size_t)(bb * NHEADS + head) * SEQ) + sg) * HDIM;
                    #pragma unroll
                    for (int ni = 0; ni < 2; ++ni) {
                        const int i = ni * 16 + lrow;
                        const float2 sc = tab[(size_t)sg * 32 + i];
                        const float x1 = acc[mi][hh * 4 + ni][r]     + bn[hh * 4 + ni];
                        const float x2 = acc[mi][hh * 4 + ni + 2][r] + bn[hh * 4 + ni + 2];
                        // reference quirk: o2 = x1*sin - x2*cos
                        const float o1 = (x1 * sc.y - x2 * sc.x) * rope_scale;
                        const float o2 = (x1 * sc.x - x2 * sc.y) * rope_scale;
                        const u32 h1 = f2bf(o1);
                        const u32 h2 = f2bf(o2);
                        Oh[ob + i]      = (u16)h1;  Ol[ob + i]      = (u16)f2bf(o1 - bf2f(h1));
                        Oh[ob + i + 32] = (u16)h2;  Ol[ob + i + 32] = (u16)f2bf(o2 - bf2f(h2));
                    }
                }
            }
        return;
    }
    // mode 1: bf16-hi V^T, transposed via LDS (stride 65), key-quartet
    // permuted; two passes (one batch parity each), vb 33KB <= 64KB.
    __syncthreads();
    u32* vb = (u32*)smem16;
    for (int p = 0; p < 2; ++p) {
        if (p) __syncthreads();
        #pragma unroll
        for (int mi = 0; mi < 2; ++mi)
            #pragma unroll
            for (int r = 0; r < 4; ++r) {
                const int mrow = w * 32 + mi * 16 + lquad * 4 + r;
                const int bb = mrow & 1;
                const int sl = mrow >> 1;
                if (bb == p) {
                    #pragma unroll
                    for (int ni = 0; ni < 8; ++ni) {
                        const int d = ni * 16 + lrow;
                        vb[d * 65 + sl] = f2bf(acc[mi][ni][r] + bn[ni]);
                    }
                }
            }
        __syncthreads();
        #pragma unroll
        for (int rep = 0; rep < 4; ++rep) {
            const int c  = rep * 256 + tid;      // 1024 chunks per pass
            const int dc = c >> 3;               // 0..127
            const int s8 = c & 7;
            __align__(8) u16 hb[8];
            #pragma unroll
            for (int j = 0; j < 8; ++j)
                hb[j] = (u16)vb[dc * 65 + s8 * 8 + j];
            const int head = nblk * 2 + (dc >> 6);
            const int dd   = dc & 63;
            const size_t orow = ((size_t)(p * NHEADS + head) * HDIM + dd) * SEQ + (m0 >> 1);
            const int blk16 = (s8 >> 1) * 16;
            const int off   = (s8 & 1) * 4;
            *(uint2*)&Oh[orow + blk16 + off]     = *(const uint2*)&hb[0];
            *(uint2*)&Oh[orow + blk16 + 8 + off] = *(const uint2*)&hb[4];
        }
    }
}

// ---------------------------------------------------------------------------
// 2-phase GEMM body for out_gemm (blocked bf16 A via gld16): BM=128,
// BN=NI*16, mode 2 fp32 row-major output. Unchanged control.
// ---------------------------------------------------------------------------
template <int NI>
__device__ __forceinline__ void gemm_body(
    int id,
    const u16* __restrict__ Ab, const u16* __restrict__ Wb,
    const float* __restrict__ bias, float* __restrict__ Of,
    u16* smem16)
{
    u16* sA = smem16;               // 2 halves x 128 rows x 64 u16
    u16* sB = smem16 + 16384;       // 2 halves x (NI*16) rows x 64 u16

    const int tid   = threadIdx.x;
    const int w     = tid >> 6;
    const int lane  = tid & 63;
    const int lrow  = lane & 15;
    const int lquad = lane >> 4;

    const int NBLK = 1024 / (NI * 16);
    const int xcd  = id & 7;
    const int jj   = id >> 3;
    const int nblk = jj & (NBLK - 1);
    const int mblk = (xcd << 2) | (jj / NBLK);
    const int n0   = nblk * NI * 16;
    const int m0   = mblk * 128;

    const int srow8 = lane >> 3;
    const int sch   = (lane & 7) ^ srow8;

    int aoffh[2], aoffl[2], boffh[NI], boffl[NI];
    #pragma unroll
    for (int mi = 0; mi < 2; ++mi) {
        const int ra = w * 32 + mi * 16 + lrow;
        aoffh[mi] = ra * 64 + ((lquad ^ (ra & 7)) << 3);
        aoffl[mi] = ra * 64 + (((lquad + 4) ^ (ra & 7)) << 3);
    }
    #pragma unroll
    for (int ni = 0; ni < NI; ++ni) {
        const int rb = ni * 16 + lrow;
        boffh[ni] = rb * 64 + ((lquad ^ (rb & 7)) << 3);
        boffl[ni] = rb * 64 + (((lquad + 4) ^ (rb & 7)) << 3);
    }

    f32x4 acc[2][NI] = {};

    auto stage = [&](int t) {
        const int h = t & 1;
        #pragma unroll
        for (int i = 0; i < 4; ++i) {
            const int slab = w * 4 + i;
            const int row  = slab * 8 + srow8;
            gld16(Ab + (size_t)(m0 + row) * 2048 + t * 64 + sch * 8,
                  sA + h * 8192 + slab * 512);
        }
        #pragma unroll
        for (int i = 0; i < NI / 2; ++i) {
            const int slab = w * (NI / 2) + i;
            const int row  = slab * 8 + srow8;
            gld16(Wb + (size_t)(n0 + row) * 2048 + t * 64 + sch * 8,
                  sB + h * (NI * 1024) + slab * 512);
        }
    };

    stage(0);
    for (int t = 0; t < 32; ++t) {
        __syncthreads();
        if (t < 31) stage(t + 1);
        const int h = t & 1;
        const u16* sAh_ = sA + h * 8192;
        const u16* sBh_ = sB + h * (NI * 1024);

        bfrag ah[2], al[2], bh[NI], bl[NI];
        #pragma unroll
        for (int mi = 0; mi < 2; ++mi) {
            ah[mi] = *(const bfrag*)&sAh_[aoffh[mi]];
            al[mi] = *(const bfrag*)&sAh_[aoffl[mi]];
        }
        #pragma unroll
        for (int ni = 0; ni < NI; ++ni) {
            bh[ni] = *(const bfrag*)&sBh_[boffh[ni]];
            bl[ni] = *(const bfrag*)&sBh_[boffl[ni]];
        }

        #pragma unroll
        for (int mi = 0; mi < 2; ++mi)
            #pragma unroll
            for (int ni = 0; ni < NI; ++ni) {
                acc[mi][ni] = __builtin_amdgcn_mfma_f32_16x16x32_bf16(ah[mi], bh[ni], acc[mi][ni], 0, 0, 0);
                acc[mi][ni] = __builtin_amdgcn_mfma_f32_16x16x32_bf16(ah[mi], bl[ni], acc[mi][ni], 0, 0, 0);
                acc[mi][ni] = __builtin_amdgcn_mfma_f32_16x16x32_bf16(al[mi], bh[ni], acc[mi][ni], 0, 0, 0);
            }
    }

    float bn[NI];
    #pragma unroll
    for (int ni = 0; ni < NI; ++ni) bn[ni] = bias[n0 + ni * 16 + lrow];

    #pragma unroll
    for (int mi = 0; mi < 2; ++mi)
        #pragma unroll
        for (int r = 0; r < 4; ++r) {
            const int m = m0 + w * 32 + mi * 16 + lquad * 4 + r;
            #pragma unroll
            for (int ni = 0; ni < NI; ++ni)
                Of[(size_t)m * 1024 + n0 + ni * 16 + lrow] = acc[mi][ni][r] + bn[ni];
        }
}

// Final projection: A = attn output (blocked). NI=4 (BN=64, grid 512,
// 48KB LDS, 3 blocks/CU). Unchanged control.
__global__ __launch_bounds__(256) void out_gemm_kernel(
    const u16* __restrict__ Ab, const u16* __restrict__ Wb,
    const float* __restrict__ bias, float* __restrict__ Of)
{
    __shared__ u16 smem16[24576];                 // 48 KB
    const int id = blockIdx.x + 16 * blockIdx.y;
    gemm_body<4>(id, Ab, Wb, bias, Of, smem16);
}

// ---------------------------------------------------------------------------
// MFMA flash attention (non-split): 32x32x16, no-max softmax (exp2, Q
// pre-scaled by log2e/8), S^T/O^T form, double-buffered K/V tiles,
// register-P, permuted V^T (hi-only). Unchanged control.
// Block = 256 threads (4 waves) = 128 q-rows; grid 512; LDS 48 KB.
// ---------------------------------------------------------------------------
__global__ __launch_bounds__(256) void attn_mfma_kernel(
    const u16* __restrict__ Qh, const u16* __restrict__ Ql,
    const u16* __restrict__ Kh, const u16* __restrict__ Kl,
    const u16* __restrict__ Vh,
    u16* __restrict__ AOb)
{
    __shared__ u16 sKh[8192], sKl[8192];   // [buf][key][dh] swizzled
    __shared__ u16 sVh[8192];              // [buf][dh][key'] swizzled (permuted)

    const int tid  = threadIdx.x;
    const int w    = tid >> 6;             // 0..3
    const int lane = tid & 63;
    const int l31  = lane & 31;
    const int g    = lane >> 5;

    const int id = blockIdx.x + 16 * blockIdx.y;   // 0..511
    const int jj = id >> 3;                        // 0..63
    const int bh = ((id & 7) << 2) | (jj >> 4);
    const int qt = jj & 15;

    const size_t qg = ((size_t)bh * SEQ + qt * 128 + w * 32 + l31) * HDIM + g * 8;
    bfrag qfh[4], qfl[4];
    #pragma unroll
    for (int ks = 0; ks < 4; ++ks) {
        qfh[ks] = *(const bfrag*)&Qh[qg + ks * 16];
        qfl[ks] = *(const bfrag*)&Ql[qg + ks * 16];
    }

    const int srow   = lane >> 3;
    const int schunk = (lane & 7) ^ srow;
    const u16* gsrc = nullptr; u16* lbase = nullptr; size_t istep = 0, ktstep = 0;
    if (w == 0) {
        gsrc = Kh + ((size_t)bh * SEQ + srow) * HDIM + schunk * 8;
        istep = 8 * 64; ktstep = 64 * 64; lbase = sKh;
    } else if (w == 1) {
        gsrc = Kl + ((size_t)bh * SEQ + srow) * HDIM + schunk * 8;
        istep = 8 * 64; ktstep = 64 * 64; lbase = sKl;
    } else if (w == 2) {
        gsrc = Vh + ((size_t)bh * HDIM + srow) * SEQ + schunk * 8;
        istep = 8 * SEQ; ktstep = 64; lbase = sVh;
    }

    int koff[2][4];
    #pragma unroll
    for (int a = 0; a < 2; ++a) {
        const int row = a * 32 + l31;
        #pragma unroll
        for (int c = 0; c < 4; ++c)
            koff[a][c] = row * 64 + (((c * 2 + g) ^ (row & 7)) << 3);
    }

    f32x16 accO[2] = {};
    float l_loc = 0.0f;

    auto stage = [&](int kt) {
        if (w < 3) {
            const u16* gp = gsrc + (size_t)kt * ktstep;
            u16* dst = lbase + (kt & 1) * 4096;
            #pragma unroll
            for (int i = 0; i < 8; ++i)
                gld16(gp + (size_t)i * istep, dst + i * 512);
        }
    };

    stage(0);
    for (int kt = 0; kt < SEQ / 64; ++kt) {
        __syncthreads();                     // tile kt ready (vmcnt drained)
        if (kt < SEQ / 64 - 1) stage(kt + 1);
        const int po = (kt & 1) * 4096;

        // ---- S^T = K Q^T (Q pre-scaled by log2e/8) : lane=q, regs=keys ----
        f32x16 accS[2] = {};
        #pragma unroll
        for (int kg = 0; kg < 2; ++kg)
            #pragma unroll
            for (int ks = 0; ks < 4; ++ks) {
                const bfrag kh_ = *(const bfrag*)&sKh[po + koff[kg][ks]];
                const bfrag kl_ = *(const bfrag*)&sKl[po + koff[kg][ks]];
                accS[kg] = __builtin_amdgcn_mfma_f32_32x32x16_bf16(kh_, qfh[ks], accS[kg], 0, 0, 0);
                accS[kg] = __builtin_amdgcn_mfma_f32_32x32x16_bf16(kh_, qfl[ks], accS[kg], 0, 0, 0);
                accS[kg] = __builtin_amdgcn_mfma_f32_32x32x16_bf16(kl_, qfh[ks], accS[kg], 0, 0, 0);
            }

        // ---- p = exp2(s') in registers (lane=q, reg=key) ----
        float pv[2][16];
        #pragma unroll
        for (int kg = 0; kg < 2; ++kg)
            #pragma unroll
            for (int r = 0; r < 16; ++r) {
                const float p = fexp2(accS[kg][r]);
                pv[kg][r] = p;
                l_loc += p;
            }

        // ---- O^T += Vh^T P^T (no exchange: permuted V^T; hi-only) ----
        #pragma unroll
        for (int kp = 0; kp < 4; ++kp) {
            const int kg = kp >> 1;
            const int t8 = (kp & 1) * 8;
            fragu ph;
            #pragma unroll
            for (int j2 = 0; j2 < 4; ++j2)
                ph.u[j2] = pk2bf(pv[kg][t8 + 2 * j2], pv[kg][t8 + 2 * j2 + 1]);
            #pragma unroll
            for (int dt = 0; dt < 2; ++dt) {
                const bfrag vh = *(const bfrag*)&sVh[po + koff[dt][kp]];
                accO[dt] = __builtin_amdgcn_mfma_f32_32x32x16_bf16(vh, ph.f, accO[dt], 0, 0, 0);
            }
        }
    }

    // ---- l: combine complementary g-halves; write BLOCKED hi/lo output ----
    const float inv = 1.0f / (l_loc + __shfl_xor(l_loc, 32));

    const int b = bh >> 4;
    const int h = bh & 15;
    const int sg = qt * 128 + w * 32 + l31;
    const int rm = sg * BATCH + b;                 // output row (0..4095)
    #pragma unroll
    for (int dt = 0; dt < 2; ++dt)
        #pragma unroll
        for (int rq = 0; rq < 4; ++rq) {
            const int j0 = 8 * rq + 4 * g;         // pos within 32-group
            const int t  = h * 2 + dt;             // group index
            __align__(8) u16 hb[4];
            __align__(8) u16 lb[4];
            #pragma unroll
            for (int i2 = 0; i2 < 4; ++i2) {
                const float v = accO[dt][rq * 4 + i2] * inv;
                const u32 hh = f2bf(v);
                hb[i2] = (u16)hh;
                lb[i2] = (u16)f2bf(v - bf2f(hh));
            }
            u16* o = AOb + (size_t)rm * 2048 + t * 64 + j0;
            *(uint2*)o        = *(const uint2*)hb;
            *(uint2*)(o + 32) = *(const uint2*)lb;
        }
}

// ---------------------------------------------------------------------------
extern "C" void kernel_launch(void* const* d_in, const int* in_sizes, int n_in,
                              void* d_out, int out_size, void* d_ws, size_t ws_size,
                              hipStream_t stream)
{
    const float* query = (const float*)d_in[0];   // READ-ONLY (never written)
    const float* key   = (const float*)d_in[1];
    const float* value = (const float*)d_in[2];
    const float* Wq    = (const float*)d_in[3];
    const float* bq    = (const float*)d_in[4];
    const float* Wk    = (const float*)d_in[5];
    const float* bk    = (const float*)d_in[6];
    const float* Wv    = (const float*)d_in[7];
    const float* bv    = (const float*)d_in[8];
    const float* Wo    = (const float*)d_in[9];
    const float* bo    = (const float*)d_in[10];
    float* out = (float*)d_out;

    // 64 MB workspace, time-multiplexed (MB offsets):
    //  Wqb [0,4) Wkb [4,8) Wvb [8,12) tab [12,12.5)  -- dead after qkv
    //  Qh [16,24) Ql [24,32) Kh [32,40) Kl [40,48) VTh [48,56)
    //  Wob [56,60)          (written in prep, read by out_gemm — never aliased)
    //  AOb blocked [0,16)   (attn output; W-packs + tab dead after qkv)
    char* wsb = (char*)d_ws;
    const size_t MB = 1024 * 1024;
    u16* Wqb = (u16*)(wsb + 0 * MB);
    u16* Wkb = (u16*)(wsb + 4 * MB);
    u16* Wvb = (u16*)(wsb + 8 * MB);
    float2* tab = (float2*)(wsb + 12 * MB);
    u16* Qh  = (u16*)(wsb + 16 * MB); u16* Ql  = (u16*)(wsb + 24 * MB);
    u16* Kh  = (u16*)(wsb + 32 * MB); u16* Kl  = (u16*)(wsb + 40 * MB);
    u16* VTh = (u16*)(wsb + 48 * MB);
    u16* Wob = (u16*)(wsb + 56 * MB);
    u16* AOb = (u16*)(wsb + 0 * MB);

    // pack weights (Wq/Wk/Wv f16-hi/bf16-lo; Wo bf16) + RoPE table
    prep_kernel<<<dim3(512, 5), 256, 0, stream>>>(
        Wq, Wk, Wv, Wo, Wqb, Wkb, Wvb, Wob, tab);
    // merged Q/K/V projections (+RoPE for Q/K; Q pre-scaled; V writes V^T hi);
    // A = raw fp32 via global_load_lds, 2-MFMA mixed f16/bf16 split
    qkv_gemm_kernel<<<dim3(16, 16, 3), 256, 0, stream>>>(
        query, key, value,
        Wqb, Wkb, Wvb, bq, bk, bv, tab, Qh, Ql, Kh, Kl, VTh);
    // attention -> blocked hi/lo (S,B,D)
    attn_mfma_kernel<<<dim3(16, 32), 256, 0, stream>>>(
        Qh, Ql, Kh, Kl, VTh, AOb);
    // output projection (NI=4: BN=64, 512 blocks)
    out_gemm_kernel<<<dim3(16, 32), 256, 0, stream>>>(AOb, Wob, bo, out);
}